// Round 7
// baseline (53.966 us; speedup 1.0000x reference)
//
#include <hip/hip_runtime.h>
#include <hip/hip_bf16.h>
#include <math.h>

#define S        8192
#define D        8
#define EPSF     1e-6f
#define LOG2E    1.442695040888963f
#define EPS_S    (LOG2E * EPSF)
#define NT       512        // 8192/16 tiles per dim

// ws byte offsets
#define ZHL_OFF  0          // 8192 rows x 16 ushort (hi[8]|lo[8]) = 262144 B
#define U_OFF    262144     // 8192 f32
#define V_OFF    294912     // 8192 f32
#define SP_OFF   327680     // 256 f32 sparse partials
#define ACC_OFF  328704     // double dsum + uint counter (16 B)

#define NSBLK    256        // sparse/gather blocks
#define NDBLK    768        // dense blocks = 256 row-pairs x 3
#define NWPP     12         // waves per row-pair

typedef __attribute__((ext_vector_type(8))) short short8_t;
typedef __attribute__((ext_vector_type(4))) float f32x4;

__device__ __forceinline__ float block_reduce_f(float v, float* sm) {
    #pragma unroll
    for (int off = 32; off > 0; off >>= 1) v += __shfl_down(v, off, 64);
    int lane = threadIdx.x & 63, wid = threadIdx.x >> 6;
    if (lane == 0) sm[wid] = v;
    __syncthreads();
    float s = 0.f;
    if (threadIdx.x == 0) {
        for (int w = 0; w < 4; ++w) s += sm[w];
    }
    return s;
}

// ---- kernel 1: gather+convert (32 rows/block) || sparse edge term ----
__global__ __launch_bounds__(256) void prep_kernel(
        const float* __restrict__ Z, const int* __restrict__ sidx,
        const int* __restrict__ ei, const int* __restrict__ ej, int ne,
        ushort* __restrict__ zhl, float* __restrict__ u, float* __restrict__ v,
        float* __restrict__ spart, double* __restrict__ dsum,
        unsigned int* __restrict__ counter) {
    __shared__ float red[4];
    int tid = threadIdx.x, bx = blockIdx.x;

    // zero the cross-kernel accumulators (any one thread; node boundary orders it)
    if (bx == 0 && tid == 255) { *dsum = 0.0; *counter = 0u; }

    // gather prologue: rows bx*32 .. bx*32+31
    if (tid < 32) {
        int t = bx * 32 + tid;
        int n = sidx[t];
        const float4* zp = (const float4*)(Z + (size_t)n * D);
        float4 a = zp[0], b = zp[1];
        float z[8] = { a.x, a.y, a.z, a.w, b.x, b.y, b.z, b.w };
        float ss = 0.f;
        short8_t h, l;
        #pragma unroll
        for (int k = 0; k < 8; ++k) {
            float zs = LOG2E * z[k];
            ss = fmaf(zs, zs, ss);
            __hip_bfloat16 hb = __float2bfloat16(zs);
            float hf = __bfloat162float(hb);
            __hip_bfloat16 lb = __float2bfloat16(zs - hf);
            h[k] = (short)__builtin_bit_cast(unsigned short, hb);
            l[k] = (short)__builtin_bit_cast(unsigned short, lb);
        }
        *(short8_t*)(zhl + (size_t)t * 16)     = h;
        *(short8_t*)(zhl + (size_t)t * 16 + 8) = l;
        u[t] = ss + 8.f * EPS_S * EPS_S;
        v[t] = ss;
    }

    // sparse positive-edge term
    float acc = 0.f;
    int nchunk = ne >> 2;
    for (int c = bx * 256 + tid; c < nchunk; c += NSBLK * 256) {
        int4 ia = ((const int4*)ei)[c];
        int4 ib = ((const int4*)ej)[c];
        int aidx[4] = { ia.x, ia.y, ia.z, ia.w };
        int bidx[4] = { ib.x, ib.y, ib.z, ib.w };
        #pragma unroll
        for (int q = 0; q < 4; ++q) {
            const float4* za = (const float4*)(Z + (size_t)aidx[q] * D);
            const float4* zb = (const float4*)(Z + (size_t)bidx[q] * D);
            float4 a0 = za[0], a1 = za[1];
            float4 b0 = zb[0], b1 = zb[1];
            float d0 = a0.x - b0.x + EPSF;
            float d1 = a0.y - b0.y + EPSF;
            float d2 = a0.z - b0.z + EPSF;
            float d3 = a0.w - b0.w + EPSF;
            float d4 = a1.x - b1.x + EPSF;
            float d5 = a1.y - b1.y + EPSF;
            float d6 = a1.z - b1.z + EPSF;
            float d7 = a1.w - b1.w + EPSF;
            float s2 = d0 * d0;
            s2 = fmaf(d1, d1, s2);
            s2 = fmaf(d2, d2, s2);
            s2 = fmaf(d3, d3, s2);
            s2 = fmaf(d4, d4, s2);
            s2 = fmaf(d5, d5, s2);
            s2 = fmaf(d6, d6, s2);
            s2 = fmaf(d7, d7, s2);
            acc += __builtin_amdgcn_sqrtf(s2);
        }
    }
    for (int e = (nchunk << 2) + bx * 256 + tid; e < ne; e += NSBLK * 256) {
        int a = ei[e], b = ej[e];
        const float4* za = (const float4*)(Z + (size_t)a * D);
        const float4* zb = (const float4*)(Z + (size_t)b * D);
        float4 a0 = za[0], a1 = za[1];
        float4 b0 = zb[0], b1 = zb[1];
        float d0 = a0.x - b0.x + EPSF, d1 = a0.y - b0.y + EPSF;
        float d2 = a0.z - b0.z + EPSF, d3 = a0.w - b0.w + EPSF;
        float d4 = a1.x - b1.x + EPSF, d5 = a1.y - b1.y + EPSF;
        float d6 = a1.z - b1.z + EPSF, d7 = a1.w - b1.w + EPSF;
        float s2 = d0 * d0;
        s2 = fmaf(d1, d1, s2); s2 = fmaf(d2, d2, s2); s2 = fmaf(d3, d3, s2);
        s2 = fmaf(d4, d4, s2); s2 = fmaf(d5, d5, s2); s2 = fmaf(d6, d6, s2);
        s2 = fmaf(d7, d7, s2);
        acc += __builtin_amdgcn_sqrtf(s2);
    }
    float s = block_reduce_f(acc, red);
    if (tid == 0) spart[bx] = s;
}

// Sweep `cnt` consecutive j-tiles starting at tj0 for fixed i-tile ti.
// Off-diagonal tiles weight 2 (mirror not enumerated), diagonal tile weight 1.
__device__ __forceinline__ void dense_sweep(const ushort* __restrict__ zhl,
                                            const float* __restrict__ v,
                                            short8_t afrag, float4 u4, int boff,
                                            int ti, int tj0, int cnt, int r,
                                            float& ax, float& ay, float& az, float& aw) {
    const ushort* bp = zhl + (size_t)(tj0 * 16 + r) * 16 + boff;
    const float*  vp = v + tj0 * 16 + r;
    short8_t bnext = *(const short8_t*)bp;
    float    vnext = vp[0];
    #pragma unroll 4
    for (int t = 0; t < cnt; ++t) {
        short8_t bcur = bnext;
        float    vcur = vnext;
        if (t + 1 < cnt) {
            bnext = *(const short8_t*)(bp + (size_t)(t + 1) * 256);
            vnext = vp[(t + 1) * 16];
        }
        float w = (tj0 + t == ti) ? 1.f : 2.f;
        f32x4 c = { 0.f, 0.f, 0.f, 0.f };
        c = __builtin_amdgcn_mfma_f32_16x16x32_bf16(afrag, bcur, c, 0, 0, 0);
        float d2_0 = fmaf(c[0], -2.f, u4.x + vcur);
        float d2_1 = fmaf(c[1], -2.f, u4.y + vcur);
        float d2_2 = fmaf(c[2], -2.f, u4.z + vcur);
        float d2_3 = fmaf(c[3], -2.f, u4.w + vcur);
        ax = fmaf(w, __builtin_amdgcn_exp2f(-__builtin_amdgcn_sqrtf(__builtin_fabsf(d2_0))), ax);
        ay = fmaf(w, __builtin_amdgcn_exp2f(-__builtin_amdgcn_sqrtf(__builtin_fabsf(d2_1))), ay);
        az = fmaf(w, __builtin_amdgcn_exp2f(-__builtin_amdgcn_sqrtf(__builtin_fabsf(d2_2))), az);
        aw = fmaf(w, __builtin_amdgcn_exp2f(-__builtin_amdgcn_sqrtf(__builtin_fabsf(d2_3))), aw);
    }
}

// ---- kernel 2: dense triangle; last-arriving block composes the output ----
__global__ __launch_bounds__(256) void dense_kernel(
        const ushort* __restrict__ zhl, const float* __restrict__ u,
        const float* __restrict__ v, const float* __restrict__ alpha,
        const float* __restrict__ spart, double* __restrict__ dsum,
        unsigned int* __restrict__ counter, float* __restrict__ out, int ne) {
    __shared__ float red[4];
    int tid = threadIdx.x, bx = blockIdx.x;
    int wave = tid >> 6, lane = tid & 63;
    int g = lane >> 4, r = lane & 15;
    int p  = bx / 3;                       // row-pair index [0,256)
    int wv = (bx - p * 3) * 4 + wave;      // wave within pair [0,12)
    int k0 = (wv * 513) / NWPP;
    int k1 = ((wv + 1) * 513) / NWPP;
    int n1 = NT - p;                       // tiles in row ti = p
    int boff = (g >> 1) * 8;               // B k-group: g<2 -> hi, g>=2 -> lo

    float ax = 0.f, ay = 0.f, az = 0.f, aw = 0.f;

    // segment A: row ti = p, tj = p + k for k in [k0, min(k1,n1))
    int eA = k1 < n1 ? k1 : n1;
    if (k0 < eA) {
        int ti = p;
        short8_t afrag = *(const short8_t*)(zhl + (size_t)(ti * 16 + r) * 16 + (g & 1) * 8);
        float4 u4 = *(const float4*)(u + ti * 16 + g * 4);
        dense_sweep(zhl, v, afrag, u4, boff, ti, p + k0, eA - k0, r, ax, ay, az, aw);
    }
    // segment B: row ti = 511-p, tj = ti + (k - n1) for k in [max(k0,n1), k1)
    int sB = k0 > n1 ? k0 : n1;
    if (sB < k1) {
        int ti = (NT - 1) - p;
        short8_t afrag = *(const short8_t*)(zhl + (size_t)(ti * 16 + r) * 16 + (g & 1) * 8);
        float4 u4 = *(const float4*)(u + ti * 16 + g * 4);
        dense_sweep(zhl, v, afrag, u4, boff, ti, ti + (sB - n1), k1 - sB, r, ax, ay, az, aw);
    }
    float s = block_reduce_f((ax + ay) + (az + aw), red);

    if (tid == 0) {
        atomicAdd(dsum, (double)s);
        __threadfence();
        unsigned int old = atomicAdd(counter, 1u);
        if (old == NDBLK - 1) {
            // last block: everyone else's dsum adds are fenced-before their
            // counter bump, so an atomic read sees the full sum.
            double Dsum = atomicAdd(dsum, 0.0);
            double Ssum = 0.0;
            for (int k = 0; k < NSBLK; ++k) Ssum += (double)spart[k];
            // diagonal entries are exp(-sqrt(8)*eps); subtract exactly
            double trace = (double)S * exp(-sqrt(8.0) * (double)EPSF);
            double offdiag = Dsum - trace;
            double a = (double)alpha[0];
            double z_pdist2 = (double)ne * a - Ssum;
            double z_pdist1 = exp(a) * 0.5 * 7.3890560989306495 * offdiag;
            out[0] = (float)(z_pdist2 - z_pdist1);
        }
    }
}

extern "C" void kernel_launch(void* const* d_in, const int* in_sizes, int n_in,
                              void* d_out, int out_size, void* d_ws, size_t ws_size,
                              hipStream_t stream) {
    const float* latent_Z = (const float*)d_in[0];
    const float* alpha    = (const float*)d_in[1];
    const int*   sidx     = (const int*)d_in[2];
    const int*   ei       = (const int*)d_in[3];
    const int*   ej       = (const int*)d_in[4];
    int ne = in_sizes[3];
    float* out = (float*)d_out;
    char*  ws  = (char*)d_ws;

    ushort* zhl     = (ushort*)(ws + ZHL_OFF);
    float*  u       = (float*)(ws + U_OFF);
    float*  v       = (float*)(ws + V_OFF);
    float*  spart   = (float*)(ws + SP_OFF);
    double* dsum    = (double*)(ws + ACC_OFF);
    unsigned int* counter = (unsigned int*)(ws + ACC_OFF + 8);

    prep_kernel<<<NSBLK, 256, 0, stream>>>(latent_Z, sidx, ei, ej, ne,
                                           zhl, u, v, spart, dsum, counter);
    dense_kernel<<<NDBLK, 256, 0, stream>>>(zhl, u, v, alpha, spart,
                                            dsum, counter, out, ne);
}